// Round 5
// baseline (233.330 us; speedup 1.0000x reference)
//
#include <hip/hip_runtime.h>

// VectorQuantizer on MI355X — round 5: token-resident MFMA block, barrier-free
// code loop, B-fragments straight from L2.
// z: [32,256,32,32] fp32; codebook: [1024,256] fp32; N=32768, K=1024, C=256.
// dist = |e|^2 - 2 z.e (|z|^2 argmin-invariant). Single-pass fp16 MFMA approx;
// tokens with approx top-2 gap <= DELTA=0.3 get an exact fp32 rescan.
//
// vq_mfma: grid 512, block 256 (4 waves). Block = 64 tokens (A resident in LDS,
// xor-swizzled, staged once); wave w scans codes [w*256, w*256+256) in 16 groups
// of 16; B half8 fragments loaded per-lane from eh (L2-hot) — NO barriers in the
// loop, top-2 carried in registers, merged once at the end. Writes idx + flags.
//
// d_out doubles as scratch: zh f16 plane @ bytes [0, 16777216) (epilogue rewrites).
// ws layout (bytes):
//   eh      @ 0        _Float16[1024*256]  (524288)
//   enorm   @ 524288   float[1024]
//   idx     @ 528384   int[32768]
//   counts  @ 659456   int[1024]
//   lsum    @ 663552   float
//   nflag   @ 663616   int
//   flag    @ 663680   int[32768]

#define BETA  0.25f
#define DELTA 0.3f

typedef _Float16 half8 __attribute__((ext_vector_type(8)));
typedef float    f32x4 __attribute__((ext_vector_type(4)));

#define GLOAD_LDS16(g, l) \
    __builtin_amdgcn_global_load_lds((const __attribute__((address_space(1))) unsigned int*)(g), \
                                     (__attribute__((address_space(3))) unsigned int*)(l), 16, 0, 0)

// ---------------------------------------------------------------------------
// Kernel 1: codebook -> eh f16 + exact |e|^2 + init accumulators. grid 256.
// ---------------------------------------------------------------------------
__global__ __launch_bounds__(256) void vq_prep_cb(
    const float* __restrict__ cb, _Float16* __restrict__ eh,
    float* __restrict__ enorm, int* __restrict__ counts,
    float* __restrict__ lsum, int* __restrict__ nflag)
{
    const int tid = threadIdx.x;
    if (blockIdx.x < 4) counts[blockIdx.x * 256 + tid] = 0;
    if (blockIdx.x == 4 && tid == 0) { *lsum = 0.0f; *nflag = 0; }

    const int lane = tid & 63;
    const int r    = blockIdx.x * 4 + (tid >> 6);
    const float4 v = *reinterpret_cast<const float4*>(cb + r * 256 + lane * 4);
    _Float16 h0 = (_Float16)v.x, h1 = (_Float16)v.y, h2 = (_Float16)v.z, h3 = (_Float16)v.w;
    *reinterpret_cast<ushort4*>(eh + r * 256 + lane * 4) =
        make_ushort4(*(unsigned short*)&h0, *(unsigned short*)&h1,
                     *(unsigned short*)&h2, *(unsigned short*)&h3);
    float s = v.x * v.x + v.y * v.y + v.z * v.z + v.w * v.w;
    #pragma unroll
    for (int off = 32; off > 0; off >>= 1) s += __shfl_down(s, off);
    if (lane == 0) enorm[r] = s;
}

// ---------------------------------------------------------------------------
// Kernel 2: z [b][c][hw] -> zh f16 token-major [n][256]. grid 512.
// ---------------------------------------------------------------------------
__global__ __launch_bounds__(256) void vq_prep_z(
    const float* __restrict__ z, _Float16* __restrict__ zh)
{
    const int tid = threadIdx.x;
    const int n0  = blockIdx.x * 64;
    const int t   = tid & 63;
    const int q   = tid >> 6;        // wave-uniform
    const float* zb = z + (n0 >> 10) * 262144 + (n0 & 1023) + t;
    _Float16*    ob = zh + (size_t)(n0 + t) * 256;
    #pragma unroll
    for (int c0 = q * 64; c0 < q * 64 + 64; c0 += 8) {
        half8 h;
        #pragma unroll
        for (int j = 0; j < 8; ++j) h[j] = (_Float16)zb[(c0 + j) * 1024];
        *reinterpret_cast<half8*>(ob + c0) = h;
    }
}

// ---------------------------------------------------------------------------
// Kernel 3: token-resident MFMA distance scan. grid 512 x 256 threads.
// A tile: 64 tokens x 256 C in LDS (32 KB), 16B chunks xor-swizzled within
// 8-chunk groups: chunk c of row r stored at (c&24)|((c&7)^(r&7)) (swizzle
// folded into global src; global_load_lds dest stays lane-linear).
// Wave w: codes [w*256, +256) in 16 groups of 16; per group: 8 B-frag global
// loads (L2-hot) + 8 k-steps x 4 MFMA; running reg top-2 per token slot.
// No __syncthreads between A-stage barrier and final merge.
// ---------------------------------------------------------------------------
__global__ __launch_bounds__(256) void vq_mfma(
    const _Float16* __restrict__ zh, const _Float16* __restrict__ eh,
    const float* __restrict__ enorm, int* __restrict__ idx,
    int* __restrict__ nflag, int* __restrict__ flaglist)
{
    __shared__ _Float16 sA[64 * 256];
    __shared__ float smv1[4][64], smv2[4][64];
    __shared__ int   smi1[4][64];

    const int tid  = threadIdx.x;
    const int lane = tid & 63;
    const int w    = tid >> 6;       // wave id: codes [w*256, w*256+256)
    const int n0   = blockIdx.x * 64;

    // ---- stage A once (32 KB, swizzled) ----
    #pragma unroll
    for (int p = 0; p < 8; ++p) {
        const int id = p * 256 + tid;
        const int r  = id >> 5;                       // token row 0..63
        const int sc = id & 31;                       // stored chunk
        const int gc = (sc & 24) | ((sc & 7) ^ (r & 7));  // global chunk
        GLOAD_LDS16(zh + (size_t)(n0 + r) * 256 + gc * 8, &sA[id * 8]);
    }

    const int nidx = lane & 15;      // column (code) within 16x16 tile
    const int g    = lane >> 4;      // k-quad

    // preload |e|^2 for this wave's 16 code-groups (overlaps the staging wait)
    float en_cg[16];
    #pragma unroll
    for (int cg = 0; cg < 16; ++cg)
        en_cg[cg] = enorm[w * 256 + cg * 16 + nidx];

    __syncthreads();

    float m1[16], m2[16]; int i1[16];
    #pragma unroll
    for (int s = 0; s < 16; ++s) { m1[s] = 1e30f; m2[s] = 1e30f; i1[s] = 0x7fffffff; }

    #pragma unroll
    for (int cg = 0; cg < 16; ++cg) {
        const int code = w * 256 + cg * 16 + nidx;
        // B fragments: lane holds B[k][n]=eh[code][k], k = ks*32 + g*8 + j
        const _Float16* brow = eh + (size_t)code * 256 + g * 8;
        half8 bq[8];
        #pragma unroll
        for (int ks = 0; ks < 8; ++ks)
            bq[ks] = *reinterpret_cast<const half8*>(brow + ks * 32);

        f32x4 acc[4] = {};
        #pragma unroll
        for (int ks = 0; ks < 8; ++ks) {
            const int cc = ks * 4 + g;
            const int sw = ((cc & 24) | ((cc & 7) ^ (nidx & 7))) * 8;
            #pragma unroll
            for (int mt = 0; mt < 4; ++mt) {
                const half8 a = *reinterpret_cast<const half8*>(
                    &sA[(mt * 16 + nidx) * 256 + sw]);   // (row&7)==(nidx&7)
                acc[mt] = __builtin_amdgcn_mfma_f32_16x16x32_f16(a, bq[ks], acc[mt], 0, 0, 0);
            }
        }
        // fold this group's distances into running top-2 (ascending code order)
        #pragma unroll
        for (int mt = 0; mt < 4; ++mt)
            #pragma unroll
            for (int reg = 0; reg < 4; ++reg) {
                const int s = mt * 4 + reg;
                const float d = fmaf(-2.0f, acc[mt][reg], en_cg[cg]);
                if (d < m1[s]) { m2[s] = m1[s]; m1[s] = d; i1[s] = code; }
                else           { m2[s] = fminf(m2[s], d); }
            }
    }

    // ---- cross-lane (16 lanes share each token slot) top-2 butterfly ----
    #pragma unroll
    for (int s = 0; s < 16; ++s) {
        float a1 = m1[s], a2 = m2[s]; int ai = i1[s];
        #pragma unroll
        for (int off = 1; off < 16; off <<= 1) {
            const float o1 = __shfl_xor(a1, off);
            const int   oi = __shfl_xor(ai, off);
            const float o2 = __shfl_xor(a2, off);
            if (o1 < a1 || (o1 == a1 && oi < ai)) { a2 = fminf(a1, o2); a1 = o1; ai = oi; }
            else                                  { a2 = fminf(a2, o1); }
        }
        if (nidx == 0) {
            const int t = (s >> 2) * 16 + g * 4 + (s & 3);   // mt*16 + g*4 + reg
            smv1[w][t] = a1; smv2[w][t] = a2; smi1[w][t] = ai;
        }
    }
    __syncthreads();

    // ---- cross-wave merge (ascending wave = ascending code blocks) ----
    if (tid < 64) {
        float b1 = smv1[0][tid], b2 = smv2[0][tid];
        int   bi = smi1[0][tid];
        #pragma unroll
        for (int ww = 1; ww < 4; ++ww) {
            const float c1 = smv1[ww][tid], c2 = smv2[ww][tid];
            const int   ci = smi1[ww][tid];
            if (c1 < b1 || (c1 == b1 && ci < bi)) { b2 = fminf(b1, c2); b1 = c1; bi = ci; }
            else                                  { b2 = fminf(b2, c1); }
        }
        idx[n0 + tid] = bi;
        if (b2 - b1 <= DELTA) {
            const int p = atomicAdd(nflag, 1);
            flaglist[p] = n0 + tid;
        }
    }
}

// ---------------------------------------------------------------------------
// Kernel 4: exact fp32 rescan, 4 tokens/block (codebook L2 reuse x4).
// grid 256 x 512 threads.
// ---------------------------------------------------------------------------
__global__ __launch_bounds__(512) void vq_rescue(
    const float* __restrict__ z, const float* __restrict__ cb,
    const float* __restrict__ enorm, const int* __restrict__ nflag,
    const int* __restrict__ flaglist, int* __restrict__ idx)
{
    __shared__ float zs[4][256];
    __shared__ float rv[4][512];
    __shared__ int   ri[4][512];
    const int tid = threadIdx.x;
    const int count = *nflag;
    for (int base = blockIdx.x * 4; base < count; base += 1024) {
        const int nt = min(4, count - base);
        __syncthreads();
        for (int t = tid >> 8; t < nt; t += 2) {
            const int n = flaglist[base + t];
            const int c = tid & 255;
            zs[t][c] = z[(n >> 10) * 262144 + c * 1024 + (n & 1023)];
        }
        __syncthreads();
        float bv[4] = {1e30f, 1e30f, 1e30f, 1e30f};
        int   bi[4] = {0x7fffffff, 0x7fffffff, 0x7fffffff, 0x7fffffff};
        #pragma unroll
        for (int j = 0; j < 2; ++j) {
            const int k = tid * 2 + j;
            const float* er = cb + k * 256;
            float s0 = 0.f, s1 = 0.f, s2 = 0.f, s3 = 0.f;
            #pragma unroll 4
            for (int c = 0; c < 256; c += 4) {
                const float4 e4 = *reinterpret_cast<const float4*>(er + c);
                s0 = fmaf(e4.x, zs[0][c], fmaf(e4.y, zs[0][c+1], fmaf(e4.z, zs[0][c+2], fmaf(e4.w, zs[0][c+3], s0))));
                s1 = fmaf(e4.x, zs[1][c], fmaf(e4.y, zs[1][c+1], fmaf(e4.z, zs[1][c+2], fmaf(e4.w, zs[1][c+3], s1))));
                s2 = fmaf(e4.x, zs[2][c], fmaf(e4.y, zs[2][c+1], fmaf(e4.z, zs[2][c+2], fmaf(e4.w, zs[2][c+3], s2))));
                s3 = fmaf(e4.x, zs[3][c], fmaf(e4.y, zs[3][c+1], fmaf(e4.z, zs[3][c+2], fmaf(e4.w, zs[3][c+3], s3))));
            }
            const float en = enorm[k];
            float d;
            d = fmaf(-2.0f, s0, en); if (d < bv[0]) { bv[0] = d; bi[0] = k; }
            d = fmaf(-2.0f, s1, en); if (d < bv[1]) { bv[1] = d; bi[1] = k; }
            d = fmaf(-2.0f, s2, en); if (d < bv[2]) { bv[2] = d; bi[2] = k; }
            d = fmaf(-2.0f, s3, en); if (d < bv[3]) { bv[3] = d; bi[3] = k; }
        }
        #pragma unroll
        for (int t = 0; t < 4; ++t) { rv[t][tid] = bv[t]; ri[t][tid] = bi[t]; }
        __syncthreads();
        const int wv = tid >> 6, lane = tid & 63;
        if (wv < nt) {
            float m = rv[wv][lane]; int mi = ri[wv][lane];
            #pragma unroll
            for (int s = 1; s < 8; ++s) {
                const float v = rv[wv][lane + s * 64]; const int ii = ri[wv][lane + s * 64];
                if (v < m || (v == m && ii < mi)) { m = v; mi = ii; }
            }
            #pragma unroll
            for (int off = 32; off > 0; off >>= 1) {
                const float ov = __shfl_down(m, off); const int oi = __shfl_down(mi, off);
                if (ov < m || (ov == m && oi < mi)) { m = ov; mi = oi; }
            }
            if (lane == 0) idx[flaglist[base + wv]] = mi;
        }
    }
}

// ---------------------------------------------------------------------------
// Kernel 5: gather z_q -> out, fused sum((z_q-z)^2) + histogram. grid 512.
// ---------------------------------------------------------------------------
__global__ __launch_bounds__(256) void vq_epilogue(
    const float* __restrict__ z, const float* __restrict__ cb,
    const int* __restrict__ idx, float* __restrict__ out,
    int* __restrict__ counts, float* __restrict__ lsum)
{
    __shared__ int   sidx[64];
    __shared__ float swsum[4];
    const int tid = threadIdx.x;
    const int n0  = blockIdx.x * 64;
    if (tid < 64) {
        const int ii = idx[n0 + tid];
        sidx[tid] = ii;
        atomicAdd(&counts[ii], 1);
    }
    __syncthreads();
    const float* zb = z   + (n0 >> 10) * 262144 + (n0 & 1023);
    float*       ob = out + (n0 >> 10) * 262144 + (n0 & 1023);
    const int t  = tid & 63;
    const int cg = tid >> 6;
    const int row = sidx[t] << 8;
    float sum = 0.0f;
    for (int c = cg; c < 256; c += 4) {
        const float q  = cb[row + c];
        const float zv = zb[c * 1024 + t];
        const float d  = q - zv;
        sum = fmaf(d, d, sum);
        ob[c * 1024 + t] = q;
    }
    #pragma unroll
    for (int off = 32; off > 0; off >>= 1) sum += __shfl_down(sum, off);
    if ((tid & 63) == 0) swsum[tid >> 6] = sum;
    __syncthreads();
    if (tid == 0) atomicAdd(lsum, swsum[0] + swsum[1] + swsum[2] + swsum[3]);
}

// ---------------------------------------------------------------------------
// Kernel 6: scalars.
// ---------------------------------------------------------------------------
__global__ __launch_bounds__(256) void vq_finalize(
    const int* __restrict__ counts, const float* __restrict__ lsum,
    float* __restrict__ outs)
{
    __shared__ float ssum[4];
    const int tid = threadIdx.x;
    float local = 0.0f;
    #pragma unroll
    for (int k = tid; k < 1024; k += 256) {
        float p = (float)counts[k] * (1.0f / 32768.0f);
        p = fmaxf(p, 1e-10f);
        local += p * logf(p);
    }
    #pragma unroll
    for (int off = 32; off > 0; off >>= 1) local += __shfl_down(local, off);
    if ((tid & 63) == 0) ssum[tid >> 6] = local;
    __syncthreads();
    if (tid == 0) {
        const float ent = ssum[0] + ssum[1] + ssum[2] + ssum[3];
        outs[0] = lsum[0] * ((1.0f + BETA) / 8388608.0f);
        outs[1] = expf(-ent);
    }
}

extern "C" void kernel_launch(void* const* d_in, const int* in_sizes, int n_in,
                              void* d_out, int out_size, void* d_ws, size_t ws_size,
                              hipStream_t stream)
{
    const float* z  = (const float*)d_in[0];
    const float* cb = (const float*)d_in[1];
    float* out = (float*)d_out;

    _Float16* zh = (_Float16*)d_out;   // scratch; epilogue rewrites all of out

    char* ws = (char*)d_ws;
    _Float16* eh     = (_Float16*)(ws);
    float*    enorm  = (float*)   (ws + 524288);
    int*      idx    = (int*)     (ws + 528384);
    int*      counts = (int*)     (ws + 659456);
    float*    lsum   = (float*)   (ws + 663552);
    int*      nflag  = (int*)     (ws + 663616);
    int*      flag   = (int*)     (ws + 663680);

    vq_prep_cb <<<256, 256, 0, stream>>>(cb, eh, enorm, counts, lsum, nflag);
    vq_prep_z  <<<512, 256, 0, stream>>>(z, zh);
    vq_mfma    <<<512, 256, 0, stream>>>(zh, eh, enorm, idx, nflag, flag);
    vq_rescue  <<<256, 512, 0, stream>>>(z, cb, enorm, nflag, flag, idx);
    vq_epilogue<<<512, 256, 0, stream>>>(z, cb, idx, out, counts, lsum);
    vq_finalize<<<1, 256, 0, stream>>>(counts, lsum, out + 8388608);
}

// Round 6
// 210.196 us; speedup vs baseline: 1.1101x; 1.1101x over previous
//
#include <hip/hip_runtime.h>

// VectorQuantizer on MI355X — round 6: operand-swapped MFMA (codes=M from L2,
// tokens=N resident in LDS), 4-slot register top-2, barrier-free code loop.
// z: [32,256,32,32] fp32; codebook: [1024,256] fp32; N=32768, K=1024, C=256.
// dist = |e|^2 - 2 z.e (|z|^2 argmin-invariant). Single-pass fp16 MFMA approx;
// tokens with approx top-2 gap <= DELTA=0.3 get an exact fp32 rescan.
//
// d_out doubles as scratch: zh f16 plane @ bytes [0, 16777216) (epilogue rewrites).
// ws layout (bytes):
//   eh      @ 0        _Float16[1024*256]  (524288)
//   enorm   @ 524288   float[1024]
//   idx     @ 528384   int[32768]
//   counts  @ 659456   int[1024]
//   lsum    @ 663552   float
//   nflag   @ 663616   int
//   flag    @ 663680   int[32768]

#define BETA  0.25f
#define DELTA 0.3f

typedef _Float16 half8 __attribute__((ext_vector_type(8)));
typedef float    f32x4 __attribute__((ext_vector_type(4)));

#define GLOAD_LDS16(g, l) \
    __builtin_amdgcn_global_load_lds((const __attribute__((address_space(1))) unsigned int*)(g), \
                                     (__attribute__((address_space(3))) unsigned int*)(l), 16, 0, 0)

// ---------------------------------------------------------------------------
// Kernel 1: codebook -> eh f16 + exact |e|^2 + init accumulators. grid 256.
// ---------------------------------------------------------------------------
__global__ __launch_bounds__(256) void vq_prep_cb(
    const float* __restrict__ cb, _Float16* __restrict__ eh,
    float* __restrict__ enorm, int* __restrict__ counts,
    float* __restrict__ lsum, int* __restrict__ nflag)
{
    const int tid = threadIdx.x;
    if (blockIdx.x < 4) counts[blockIdx.x * 256 + tid] = 0;
    if (blockIdx.x == 4 && tid == 0) { *lsum = 0.0f; *nflag = 0; }

    const int lane = tid & 63;
    const int r    = blockIdx.x * 4 + (tid >> 6);
    const float4 v = *reinterpret_cast<const float4*>(cb + r * 256 + lane * 4);
    _Float16 h0 = (_Float16)v.x, h1 = (_Float16)v.y, h2 = (_Float16)v.z, h3 = (_Float16)v.w;
    *reinterpret_cast<ushort4*>(eh + r * 256 + lane * 4) =
        make_ushort4(*(unsigned short*)&h0, *(unsigned short*)&h1,
                     *(unsigned short*)&h2, *(unsigned short*)&h3);
    float s = v.x * v.x + v.y * v.y + v.z * v.z + v.w * v.w;
    #pragma unroll
    for (int off = 32; off > 0; off >>= 1) s += __shfl_down(s, off);
    if (lane == 0) enorm[r] = s;
}

// ---------------------------------------------------------------------------
// Kernel 2: z [b][c][hw] -> zh f16 token-major [n][256]. grid 2048:
// block = 64 tokens x 64 channels (4x the round-5 block count for occupancy).
// ---------------------------------------------------------------------------
__global__ __launch_bounds__(256) void vq_prep_z(
    const float* __restrict__ z, _Float16* __restrict__ zh)
{
    const int tid   = threadIdx.x;
    const int ntile = blockIdx.x >> 2;
    const int ctile = blockIdx.x & 3;
    const int n0    = ntile * 64;
    const int t     = tid & 63;
    const int cb0   = ctile * 64 + (tid >> 6) * 16;
    const float* zb = z + (n0 >> 10) * 262144 + (n0 & 1023) + t;
    float v[16];
    #pragma unroll
    for (int j = 0; j < 16; ++j) v[j] = zb[(cb0 + j) * 1024];   // coalesced, 16-deep ILP
    half8 h0, h1;
    #pragma unroll
    for (int j = 0; j < 8; ++j) { h0[j] = (_Float16)v[j]; h1[j] = (_Float16)v[j + 8]; }
    _Float16* ob = zh + (size_t)(n0 + t) * 256 + cb0;
    *reinterpret_cast<half8*>(ob)     = h0;
    *reinterpret_cast<half8*>(ob + 8) = h1;
}

// ---------------------------------------------------------------------------
// Kernel 3: MFMA distance scan, operand-swapped. grid 512 x 256 threads.
// B tile: 64 tokens x 256 C in LDS (32 KB), 16B chunks xor-swizzled
// ((c&24)|((c&7)^(r&7)), swizzle folded into global src address).
// Wave w scans codes [w*256,+256) in 4 tiles of 64 codes: A-frags per-lane
// from eh (L2-hot), no barriers in the loop. D: col=token=lane&15,
// row=code=(lane>>4)*4+reg+mt*16 -> per-lane top-2 in 4 slots only.
// ---------------------------------------------------------------------------
__global__ __launch_bounds__(256) void vq_mfma(
    const _Float16* __restrict__ zh, const _Float16* __restrict__ eh,
    const float* __restrict__ enorm, int* __restrict__ idx,
    int* __restrict__ nflag, int* __restrict__ flaglist)
{
    __shared__ _Float16 sB[64 * 256];
    __shared__ float smv1[4][64], smv2[4][64];
    __shared__ int   smi1[4][64];

    const int tid  = threadIdx.x;
    const int lane = tid & 63;
    const int w    = tid >> 6;
    const int n0   = blockIdx.x * 64;

    // ---- stage B (tokens) once, swizzled ----
    #pragma unroll
    for (int p = 0; p < 8; ++p) {
        const int id = p * 256 + tid;
        const int r  = id >> 5;
        const int sc = id & 31;
        const int gc = (sc & 24) | ((sc & 7) ^ (r & 7));
        GLOAD_LDS16(zh + (size_t)(n0 + r) * 256 + gc * 8, &sB[id * 8]);
    }

    const int nidx = lane & 15;   // token column
    const int g    = lane >> 4;   // k-quad / code sub-row

    __syncthreads();

    float m1[4] = {1e30f, 1e30f, 1e30f, 1e30f};
    float m2[4] = {1e30f, 1e30f, 1e30f, 1e30f};
    int   i1[4] = {0x7fffffff, 0x7fffffff, 0x7fffffff, 0x7fffffff};

    for (int ct = 0; ct < 4; ++ct) {
        const int cbase = w * 256 + ct * 64;
        const _Float16* arow = eh + (size_t)(cbase + nidx) * 256 + g * 8;

        f32x4 acc[4][4] = {};
        #pragma unroll
        for (int ks = 0; ks < 8; ++ks) {
            half8 a[4], b[4];
            #pragma unroll
            for (int mt = 0; mt < 4; ++mt)
                a[mt] = *reinterpret_cast<const half8*>(arow + mt * 4096 + ks * 32);
            const int cc = ks * 4 + g;
            #pragma unroll
            for (int nt = 0; nt < 4; ++nt) {
                const int row = nt * 16 + nidx;
                const int sw  = ((cc & 24) | ((cc & 7) ^ (row & 7))) * 8;
                b[nt] = *reinterpret_cast<const half8*>(&sB[row * 256 + sw]);
            }
            #pragma unroll
            for (int mt = 0; mt < 4; ++mt)
                #pragma unroll
                for (int nt = 0; nt < 4; ++nt)
                    acc[mt][nt] = __builtin_amdgcn_mfma_f32_16x16x32_f16(a[mt], b[nt], acc[mt][nt], 0, 0, 0);
        }
        // fold: lane's codes = cbase + mt*16 + g*4 + reg (ascending in mt,reg)
        #pragma unroll
        for (int mt = 0; mt < 4; ++mt) {
            const int c0 = cbase + mt * 16 + g * 4;
            const float4 en4 = *reinterpret_cast<const float4*>(enorm + c0);
            #pragma unroll
            for (int reg = 0; reg < 4; ++reg) {
                const float en = reg == 0 ? en4.x : reg == 1 ? en4.y : reg == 2 ? en4.z : en4.w;
                #pragma unroll
                for (int nt = 0; nt < 4; ++nt) {
                    const float d = fmaf(-2.0f, acc[mt][nt][reg], en);
                    if (d < m1[nt]) { m2[nt] = m1[nt]; m1[nt] = d; i1[nt] = c0 + reg; }
                    else            { m2[nt] = fminf(m2[nt], d); }
                }
            }
        }
    }

    // ---- merge the 4 g-lanes sharing each token column (xor 16, 32) ----
    #pragma unroll
    for (int nt = 0; nt < 4; ++nt) {
        float a1 = m1[nt], a2 = m2[nt]; int ai = i1[nt];
        #pragma unroll
        for (int off = 16; off < 64; off <<= 1) {
            const float o1 = __shfl_xor(a1, off);
            const int   oi = __shfl_xor(ai, off);
            const float o2 = __shfl_xor(a2, off);
            if (o1 < a1 || (o1 == a1 && oi < ai)) { a2 = fminf(a1, o2); a1 = o1; ai = oi; }
            else                                  { a2 = fminf(a2, o1); }
        }
        if (g == 0) {
            smv1[w][nt * 16 + nidx] = a1;
            smv2[w][nt * 16 + nidx] = a2;
            smi1[w][nt * 16 + nidx] = ai;
        }
    }
    __syncthreads();

    // ---- cross-wave merge (waves = ascending code blocks) ----
    if (tid < 64) {
        float b1 = smv1[0][tid], b2 = smv2[0][tid];
        int   bi = smi1[0][tid];
        #pragma unroll
        for (int ww = 1; ww < 4; ++ww) {
            const float c1 = smv1[ww][tid], c2 = smv2[ww][tid];
            const int   ci = smi1[ww][tid];
            if (c1 < b1 || (c1 == b1 && ci < bi)) { b2 = fminf(b1, c2); b1 = c1; bi = ci; }
            else                                  { b2 = fminf(b2, c1); }
        }
        idx[n0 + tid] = bi;
        if (b2 - b1 <= DELTA) {
            const int p = atomicAdd(nflag, 1);
            flaglist[p] = n0 + tid;
        }
    }
}

// ---------------------------------------------------------------------------
// Kernel 4: exact fp32 rescan, 4 tokens/block (codebook L2 reuse x4).
// grid 256 x 512 threads.
// ---------------------------------------------------------------------------
__global__ __launch_bounds__(512) void vq_rescue(
    const float* __restrict__ z, const float* __restrict__ cb,
    const float* __restrict__ enorm, const int* __restrict__ nflag,
    const int* __restrict__ flaglist, int* __restrict__ idx)
{
    __shared__ float zs[4][256];
    __shared__ float rv[4][512];
    __shared__ int   ri[4][512];
    const int tid = threadIdx.x;
    const int count = *nflag;
    for (int base = blockIdx.x * 4; base < count; base += 1024) {
        const int nt = min(4, count - base);
        __syncthreads();
        for (int t = tid >> 8; t < nt; t += 2) {
            const int n = flaglist[base + t];
            const int c = tid & 255;
            zs[t][c] = z[(n >> 10) * 262144 + c * 1024 + (n & 1023)];
        }
        __syncthreads();
        float bv[4] = {1e30f, 1e30f, 1e30f, 1e30f};
        int   bi[4] = {0x7fffffff, 0x7fffffff, 0x7fffffff, 0x7fffffff};
        #pragma unroll
        for (int j = 0; j < 2; ++j) {
            const int k = tid * 2 + j;
            const float* er = cb + k * 256;
            float s0 = 0.f, s1 = 0.f, s2 = 0.f, s3 = 0.f;
            #pragma unroll 4
            for (int c = 0; c < 256; c += 4) {
                const float4 e4 = *reinterpret_cast<const float4*>(er + c);
                s0 = fmaf(e4.x, zs[0][c], fmaf(e4.y, zs[0][c+1], fmaf(e4.z, zs[0][c+2], fmaf(e4.w, zs[0][c+3], s0))));
                s1 = fmaf(e4.x, zs[1][c], fmaf(e4.y, zs[1][c+1], fmaf(e4.z, zs[1][c+2], fmaf(e4.w, zs[1][c+3], s1))));
                s2 = fmaf(e4.x, zs[2][c], fmaf(e4.y, zs[2][c+1], fmaf(e4.z, zs[2][c+2], fmaf(e4.w, zs[2][c+3], s2))));
                s3 = fmaf(e4.x, zs[3][c], fmaf(e4.y, zs[3][c+1], fmaf(e4.z, zs[3][c+2], fmaf(e4.w, zs[3][c+3], s3))));
            }
            const float en = enorm[k];
            float d;
            d = fmaf(-2.0f, s0, en); if (d < bv[0]) { bv[0] = d; bi[0] = k; }
            d = fmaf(-2.0f, s1, en); if (d < bv[1]) { bv[1] = d; bi[1] = k; }
            d = fmaf(-2.0f, s2, en); if (d < bv[2]) { bv[2] = d; bi[2] = k; }
            d = fmaf(-2.0f, s3, en); if (d < bv[3]) { bv[3] = d; bi[3] = k; }
        }
        #pragma unroll
        for (int t = 0; t < 4; ++t) { rv[t][tid] = bv[t]; ri[t][tid] = bi[t]; }
        __syncthreads();
        const int wv = tid >> 6, lane = tid & 63;
        if (wv < nt) {
            float m = rv[wv][lane]; int mi = ri[wv][lane];
            #pragma unroll
            for (int s = 1; s < 8; ++s) {
                const float v = rv[wv][lane + s * 64]; const int ii = ri[wv][lane + s * 64];
                if (v < m || (v == m && ii < mi)) { m = v; mi = ii; }
            }
            #pragma unroll
            for (int off = 32; off > 0; off >>= 1) {
                const float ov = __shfl_down(m, off); const int oi = __shfl_down(mi, off);
                if (ov < m || (ov == m && oi < mi)) { m = ov; mi = oi; }
            }
            if (lane == 0) idx[flaglist[base + wv]] = mi;
        }
    }
}

// ---------------------------------------------------------------------------
// Kernel 5: gather z_q -> out, fused sum((z_q-z)^2) + histogram. grid 2048:
// block = 64 tokens x 64 channels; histogram only from ctile 0.
// ---------------------------------------------------------------------------
__global__ __launch_bounds__(256) void vq_epilogue(
    const float* __restrict__ z, const float* __restrict__ cb,
    const int* __restrict__ idx, float* __restrict__ out,
    int* __restrict__ counts, float* __restrict__ lsum)
{
    __shared__ int   sidx[64];
    __shared__ float swsum[4];
    const int tid   = threadIdx.x;
    const int ntile = blockIdx.x >> 2;
    const int ctile = blockIdx.x & 3;
    const int n0    = ntile * 64;
    if (tid < 64) {
        const int ii = idx[n0 + tid];
        sidx[tid] = ii;
        if (ctile == 0) atomicAdd(&counts[ii], 1);
    }
    __syncthreads();
    const float* zb = z   + (n0 >> 10) * 262144 + (n0 & 1023);
    float*       ob = out + (n0 >> 10) * 262144 + (n0 & 1023);
    const int t   = tid & 63;
    const int cb0 = ctile * 64 + (tid >> 6) * 16;
    const int row = sidx[t] << 8;
    float sum = 0.0f;
    #pragma unroll
    for (int j = 0; j < 16; ++j) {
        const int c = cb0 + j;
        const float q  = cb[row + c];
        const float zv = zb[c * 1024 + t];
        const float d  = q - zv;
        sum = fmaf(d, d, sum);
        ob[c * 1024 + t] = q;
    }
    #pragma unroll
    for (int off = 32; off > 0; off >>= 1) sum += __shfl_down(sum, off);
    if ((tid & 63) == 0) swsum[tid >> 6] = sum;
    __syncthreads();
    if (tid == 0) atomicAdd(lsum, swsum[0] + swsum[1] + swsum[2] + swsum[3]);
}

// ---------------------------------------------------------------------------
// Kernel 6: scalars.
// ---------------------------------------------------------------------------
__global__ __launch_bounds__(256) void vq_finalize(
    const int* __restrict__ counts, const float* __restrict__ lsum,
    float* __restrict__ outs)
{
    __shared__ float ssum[4];
    const int tid = threadIdx.x;
    float local = 0.0f;
    #pragma unroll
    for (int k = tid; k < 1024; k += 256) {
        float p = (float)counts[k] * (1.0f / 32768.0f);
        p = fmaxf(p, 1e-10f);
        local += p * logf(p);
    }
    #pragma unroll
    for (int off = 32; off > 0; off >>= 1) local += __shfl_down(local, off);
    if ((tid & 63) == 0) ssum[tid >> 6] = local;
    __syncthreads();
    if (tid == 0) {
        const float ent = ssum[0] + ssum[1] + ssum[2] + ssum[3];
        outs[0] = lsum[0] * ((1.0f + BETA) / 8388608.0f);
        outs[1] = expf(-ent);
    }
}

extern "C" void kernel_launch(void* const* d_in, const int* in_sizes, int n_in,
                              void* d_out, int out_size, void* d_ws, size_t ws_size,
                              hipStream_t stream)
{
    const float* z  = (const float*)d_in[0];
    const float* cb = (const float*)d_in[1];
    float* out = (float*)d_out;

    _Float16* zh = (_Float16*)d_out;   // scratch; epilogue rewrites all of out

    char* ws = (char*)d_ws;
    _Float16* eh     = (_Float16*)(ws);
    float*    enorm  = (float*)   (ws + 524288);
    int*      idx    = (int*)     (ws + 528384);
    int*      counts = (int*)     (ws + 659456);
    float*    lsum   = (float*)   (ws + 663552);
    int*      nflag  = (int*)     (ws + 663616);
    int*      flag   = (int*)     (ws + 663680);

    vq_prep_cb <<<256, 256, 0, stream>>>(cb, eh, enorm, counts, lsum, nflag);
    vq_prep_z  <<<2048, 256, 0, stream>>>(z, zh);
    vq_mfma    <<<512, 256, 0, stream>>>(zh, eh, enorm, idx, nflag, flag);
    vq_rescue  <<<256, 512, 0, stream>>>(z, cb, enorm, nflag, flag, idx);
    vq_epilogue<<<2048, 256, 0, stream>>>(z, cb, idx, out, counts, lsum);
    vq_finalize<<<1, 256, 0, stream>>>(counts, lsum, out + 8388608);
}